// Round 7
// baseline (6366.864 us; speedup 1.0000x reference)
//
#include <hip/hip_runtime.h>

typedef _Float16 f16;
typedef _Float16 f16x4v __attribute__((ext_vector_type(4)));
typedef _Float16 f16x8  __attribute__((ext_vector_type(8)));
typedef float    f32x4  __attribute__((ext_vector_type(4)));
typedef unsigned long long u64;
typedef unsigned int u32;

#define NB 32
#define NT 512
#define NF 512
#define NH 512
#define NG 2048   // 4*NH gate columns

// workspace layout (bytes)
static const size_t XH_OFF   = 0;
static const size_t XH_BYTES = (size_t)NB*NT*NF*2;        // 16 MiB fp16 x
static const size_t WT_OFF   = XH_OFF + XH_BYTES;
static const size_t WT_BYTES = (size_t)2*NG*1024*2;       //  8 MiB Wt[dir][col][k] fp16
static const size_t GX_OFF   = WT_OFF + WT_BYTES;
static const size_t GX_BYTES = (size_t)2*NT*65536*2;      // 128 MiB gxp[dir][slot][rank][wv][lane][32]
static const size_t HB_OFF   = GX_OFF + GX_BYTES;
static const size_t HB_BYTES = (size_t)2*2*NB*NH*2;       // 128 KiB h exchange [slot][dir][b][k]

__device__ __forceinline__ float sigf(float x){ return 1.0f/(1.0f+__expf(-x)); }
__device__ __forceinline__ float tanh_f(float x){ return 1.0f - 2.0f/(__expf(2.0f*x)+1.0f); }

__global__ void k_zero(float4* o, size_t no, uint4* z, size_t nz) {
  size_t i = (size_t)blockIdx.x*blockDim.x + threadIdx.x;
  size_t st = (size_t)gridDim.x*blockDim.x;
  float4 fz = make_float4(0.f,0.f,0.f,0.f);
  uint4  uz = make_uint4(0u,0u,0u,0u);
  for (size_t j=i; j<no; j+=st) o[j]=fz;
  for (size_t j=i; j<nz; j+=st) z[j]=uz;
}

__global__ void k_cvt(const float* __restrict__ x, f16* __restrict__ xh) {
  size_t i = ((size_t)blockIdx.x*blockDim.x + threadIdx.x)*4;
  float4 v = *(const float4*)(x+i);
  f16x4v h; h[0]=(f16)v.x; h[1]=(f16)v.y; h[2]=(f16)v.z; h[3]=(f16)v.w;
  *(f16x4v*)(xh+i) = h;
}

// W [1024][2048] f32 -> Wt[dir][col 2048][k 1024] fp16 (tiled transpose)
__global__ void k_tw(const float* __restrict__ Wfw, const float* __restrict__ Wbw,
                     f16* __restrict__ Wt) {
  __shared__ f16 tile[32][33];
  int b = blockIdx.x;
  int dir = b >> 11; int rem = b & 2047;
  int kt = rem >> 6, ct = rem & 63;
  const float* W = dir ? Wbw : Wfw;
  int tx = threadIdx.x & 31, ty0 = threadIdx.x >> 5;
  int k0 = kt*32, c0 = ct*32;
  for (int yy=ty0; yy<32; yy+=8)
    tile[yy][tx] = (f16)W[(size_t)(k0+yy)*2048 + c0 + tx];
  __syncthreads();
  f16* Wd = Wt + (size_t)dir*2048*1024;
  for (int yy=ty0; yy<32; yy+=8)
    Wd[(size_t)(c0+yy)*1024 + k0 + tx] = tile[tx][yy];
}

// gxp[dir][slot][rank][wv][lane 64][32] = x@Wx + bias, in consumer-lane-fragment
// order (inner = g*8 + mi*4 + rr, b = mi*16 + q*4 + rr, lane = q*16 + cc).
// Backward-direction time reversal folded into slot (bijection per batch).
// 128x128 tile GEMM, BK=32, 4 waves, global_load_lds + 16B XOR swizzle.
__global__ __launch_bounds__(256) void k_gx(const f16* __restrict__ xh,
    const f16* __restrict__ Wt, const float* __restrict__ bfw,
    const float* __restrict__ bbw, const int* __restrict__ seqlen,
    f16* __restrict__ gxp)
{
  __shared__ f16 As[128*32];
  __shared__ f16 Bs[128*32];
  int bm0 = blockIdx.x * 128;
  int bn0 = blockIdx.y * 128;
  int dir = blockIdx.z;
  const f16* Wd = Wt + (size_t)dir*NG*1024;
  const float* bias = dir ? bbw : bfw;

  int tid = threadIdx.x;
  int w = tid>>6, lane = tid&63;
  int cc = lane&15, q = lane>>4;
  int wm = w>>1, wn = w&1;

  f32x4 acc[4][4];
#pragma unroll
  for (int i=0;i<4;++i)
#pragma unroll
    for (int j=0;j<4;++j) acc[i][j] = (f32x4){0.f,0.f,0.f,0.f};

  for (int kt=0; kt<16; ++kt) {
    int k0 = kt*32;
#pragma unroll
    for (int c=0;c<2;++c) {
      int ch = w*2 + c;
      int row = ch*16 + (lane>>2);
      int cph = (lane&3)*16;
      int clg = cph ^ (((row>>1)&3)<<4);
      const f16* ga = xh + (size_t)(bm0+row)*NF   + k0 + (clg>>1);
      const f16* gb = Wd + (size_t)(bn0+row)*1024 + k0 + (clg>>1);
      __builtin_amdgcn_global_load_lds(
          (const __attribute__((address_space(1))) u32*)ga,
          (__attribute__((address_space(3))) u32*)(As + ch*512), 16, 0, 0);
      __builtin_amdgcn_global_load_lds(
          (const __attribute__((address_space(1))) u32*)gb,
          (__attribute__((address_space(3))) u32*)(Bs + ch*512), 16, 0, 0);
    }
    __syncthreads();

    f16x8 av[4], bv[4];
#pragma unroll
    for (int mi=0;mi<4;++mi) {
      int r = wm*64 + mi*16 + cc;
      int sw = ((r>>1)&3)<<4;
      u64 lo = *(const u64*)&As[r*32 + ((((q*8)   ) ^ sw)>>1)];
      u64 hi = *(const u64*)&As[r*32 + ((((q*8)+32) ^ sw)>>1)];
      f16x4v l4 = __builtin_bit_cast(f16x4v, lo);
      f16x4v h4 = __builtin_bit_cast(f16x4v, hi);
      f16x8 a; a[0]=l4[0];a[1]=l4[1];a[2]=l4[2];a[3]=l4[3];
      a[4]=h4[0];a[5]=h4[1];a[6]=h4[2];a[7]=h4[3];
      av[mi]=a;
    }
#pragma unroll
    for (int ni=0;ni<4;++ni) {
      int r = wn*64 + ni*16 + cc;
      int sw = ((r>>1)&3)<<4;
      u64 lo = *(const u64*)&Bs[r*32 + ((((q*8)   ) ^ sw)>>1)];
      u64 hi = *(const u64*)&Bs[r*32 + ((((q*8)+32) ^ sw)>>1)];
      f16x4v l4 = __builtin_bit_cast(f16x4v, lo);
      f16x4v h4 = __builtin_bit_cast(f16x4v, hi);
      f16x8 a; a[0]=l4[0];a[1]=l4[1];a[2]=l4[2];a[3]=l4[3];
      a[4]=h4[0];a[5]=h4[1];a[6]=h4[2];a[7]=h4[3];
      bv[ni]=a;
    }
#pragma unroll
    for (int mi=0;mi<4;++mi)
#pragma unroll
      for (int ni=0;ni<4;++ni)
        acc[mi][ni] = __builtin_amdgcn_mfma_f32_16x16x32_f16(av[mi], bv[ni], acc[mi][ni], 0,0,0);
    __syncthreads();
  }

  // epilogue: permuted scatter into consumer-fragment layout
  int b = bm0 >> 9;              // this block's single batch
  int L = seqlen[b];
  int boff  = (b>>4)*4 + (b&3);  // mi_c*4 + rr_c
  int blane = ((b>>2)&3)*16;     // q_c*16
  f16* gd = gxp + (size_t)dir*NT*65536;
#pragma unroll
  for (int ni=0;ni<4;++ni) {
    int col = bn0 + wn*64 + ni*16 + cc;
    int g = col>>9, n = col&511;
    int rk = n>>6, wv = (n>>4)&3, ccc = n&15;
    float bvl = bias[col];
    size_t coff = (size_t)(((rk*4 + wv)*64 + blane + ccc)*32 + g*8 + boff);
#pragma unroll
    for (int mi=0;mi<4;++mi)
#pragma unroll
      for (int rr=0;rr<4;++rr) {
        int t = (bm0&511) + wm*64 + mi*16 + q*4 + rr;
        int slot = dir ? ((t < L) ? (L-1-t) : t) : t;
        gd[(size_t)slot*65536 + coff] = (f16)(acc[mi][ni][rr] + bvl);
      }
  }
}

// Persistent recurrence, ZERO sync instructions.
// 16 blocks: dir=bid>>3, rank=bid&7; wave w owns cols [rank*64+w*16, +16).
// h exchange: 2-slot ping-pong (slot = t&1), step tag = ((t+1)>>1)&1 in the
// LSB of the first f16 of every u64. Consumers poll the data u64s directly:
// alternating tags + same-address coherence monotonicity make stale data
// self-identifying; depth-2 reuse is race-free because a producer reaches
// step s+2 only after consuming data that postdates all readers' step-s loads.
// No flags, no fences, no vmcnt drains, no __syncthreads.
__global__ __launch_bounds__(256, 1) __attribute__((amdgpu_waves_per_eu(1, 1)))
void k_rnn(const f16* __restrict__ gxp, const f16* __restrict__ Wt,
           u64* hbuf, const int* __restrict__ seqlen, float* __restrict__ out)
{
  int bid = blockIdx.x;
  int dir = bid >> 3, rank = bid & 7;
  int tid = threadIdx.x;
  int w = tid>>6, lane = tid&63, cc = lane&15, q = lane>>4;
  int ncol0 = rank*64 + w*16;

  // Persistent W_h fragments: col = g*512 + ncol0 + cc, k = 512 + kk*32 + q*4 (+16)
  f16x8 Wf[16][4];
  {
    const f16* Wd = Wt + (size_t)dir*NG*1024;
#pragma unroll
    for (int kk=0;kk<16;++kk)
#pragma unroll
      for (int g=0;g<4;++g) {
        const f16* pp = Wd + (size_t)(g*NH + ncol0 + cc)*1024 + 512 + kk*32 + q*4;
        f16x4v lo = *(const f16x4v*)pp;
        f16x4v hi = *(const f16x4v*)(pp+16);
        f16x8 a; a[0]=lo[0];a[1]=lo[1];a[2]=lo[2];a[3]=lo[3];
        a[4]=hi[0];a[5]=hi[1];a[6]=hi[2];a[7]=hi[3];
        Wf[kk][g] = a;
      }
  }

  int Lr[2][4];
#pragma unroll
  for (int mi=0;mi<2;++mi)
#pragma unroll
    for (int rr=0;rr<4;++rr)
      Lr[mi][rr] = seqlen[mi*16 + q*4 + rr];

  float cst[2][4], hst[2][4];
#pragma unroll
  for (int mi=0;mi<2;++mi)
#pragma unroll
    for (int rr=0;rr<4;++rr) { cst[mi][rr]=0.f; hst[mi][rr]=0.f; }

  const f16* gwave = gxp + ((size_t)(((dir*NT)*8 + rank)*4 + w))*2048 + (size_t)lane*32;
  float* outd = out + dir*NH;

  for (int s = 0; s < NT; ++s) {
    int slot_r = s & 1, slot_w = (s+1) & 1;
    u64 tg_r = (u64)(((s+1)>>1) & 1);
    u32 tg_w = (u32)(((s+2)>>1) & 1);

    // gx: 4 coalesced dwordx4 (fragment-contiguous; reversal pre-folded)
    const uint4* gp = (const uint4*)(gwave + (size_t)s*65536);
    uint4 g0 = gp[0], g1 = gp[1], g2 = gp[2], g3 = gp[3];

    f32x4 acc[4][2];
#pragma unroll
    for (int g=0;g<4;++g)
#pragma unroll
      for (int mi=0;mi<2;++mi) acc[g][mi] = (f32x4){0.f,0.f,0.f,0.f};

    if (s > 0) {
      const u64* hb = hbuf + (size_t)(slot_r*2+dir)*NB*(NH/4);
      const u64* pb0 = hb + (size_t)cc*(NH/4) + q;        // mi=0 batches
      const u64* pb1 = hb + (size_t)(16+cc)*(NH/4) + q;   // mi=1 batches
      u64 vb[8][4];
      // prologue: issue 8 kk-groups (32 loads) up front
#pragma unroll
      for (int kk=0;kk<8;++kk) {
        vb[kk][0] = __hip_atomic_load(pb0 + kk*8,     __ATOMIC_RELAXED, __HIP_MEMORY_SCOPE_AGENT);
        vb[kk][1] = __hip_atomic_load(pb0 + kk*8 + 4, __ATOMIC_RELAXED, __HIP_MEMORY_SCOPE_AGENT);
        vb[kk][2] = __hip_atomic_load(pb1 + kk*8,     __ATOMIC_RELAXED, __HIP_MEMORY_SCOPE_AGENT);
        vb[kk][3] = __hip_atomic_load(pb1 + kk*8 + 4, __ATOMIC_RELAXED, __HIP_MEMORY_SCOPE_AGENT);
      }
#pragma unroll
      for (int kk=0;kk<16;++kk) {
        int sl = kk & 7;
        u64 a0 = vb[sl][0], a1 = vb[sl][1], a2 = vb[sl][2], a3 = vb[sl][3];
        for (;;) {
          u64 bad = ((a0 ^ tg_r) | (a1 ^ tg_r) | (a2 ^ tg_r) | (a3 ^ tg_r)) & 1ull;
          if (__all(bad == 0)) break;
          a0 = __hip_atomic_load(pb0 + kk*8,     __ATOMIC_RELAXED, __HIP_MEMORY_SCOPE_AGENT);
          a1 = __hip_atomic_load(pb0 + kk*8 + 4, __ATOMIC_RELAXED, __HIP_MEMORY_SCOPE_AGENT);
          a2 = __hip_atomic_load(pb1 + kk*8,     __ATOMIC_RELAXED, __HIP_MEMORY_SCOPE_AGENT);
          a3 = __hip_atomic_load(pb1 + kk*8 + 4, __ATOMIC_RELAXED, __HIP_MEMORY_SCOPE_AGENT);
        }
        f16x4v l0 = __builtin_bit_cast(f16x4v, a0), h0 = __builtin_bit_cast(f16x4v, a1);
        f16x4v l1 = __builtin_bit_cast(f16x4v, a2), h1 = __builtin_bit_cast(f16x4v, a3);
        f16x8 af0, af1;
        af0[0]=l0[0];af0[1]=l0[1];af0[2]=l0[2];af0[3]=l0[3];
        af0[4]=h0[0];af0[5]=h0[1];af0[6]=h0[2];af0[7]=h0[3];
        af1[0]=l1[0];af1[1]=l1[1];af1[2]=l1[2];af1[3]=l1[3];
        af1[4]=h1[0];af1[5]=h1[1];af1[6]=h1[2];af1[7]=h1[3];
#pragma unroll
        for (int g=0;g<4;++g) {
          acc[g][0] = __builtin_amdgcn_mfma_f32_16x16x32_f16(af0, Wf[kk][g], acc[g][0], 0,0,0);
          acc[g][1] = __builtin_amdgcn_mfma_f32_16x16x32_f16(af1, Wf[kk][g], acc[g][1], 0,0,0);
        }
        if (kk < 8) {
          int kn = kk + 8;
          vb[sl][0] = __hip_atomic_load(pb0 + kn*8,     __ATOMIC_RELAXED, __HIP_MEMORY_SCOPE_AGENT);
          vb[sl][1] = __hip_atomic_load(pb0 + kn*8 + 4, __ATOMIC_RELAXED, __HIP_MEMORY_SCOPE_AGENT);
          vb[sl][2] = __hip_atomic_load(pb1 + kn*8,     __ATOMIC_RELAXED, __HIP_MEMORY_SCOPE_AGENT);
          vb[sl][3] = __hip_atomic_load(pb1 + kn*8 + 4, __ATOMIC_RELAXED, __HIP_MEMORY_SCOPE_AGENT);
        }
      }
    }

    // unpack gx fragments: inner order = g*8 + mi*4 + rr
    f16x8 c0 = __builtin_bit_cast(f16x8, g0);
    f16x8 c1 = __builtin_bit_cast(f16x8, g1);
    f16x8 c2 = __builtin_bit_cast(f16x8, g2);
    f16x8 c3 = __builtin_bit_cast(f16x8, g3);

    // activations
    float hnv[2][4];
#pragma unroll
    for (int mi=0;mi<2;++mi)
#pragma unroll
      for (int rr=0;rr<4;++rr) {
        float gi = acc[0][mi][rr] + (float)c0[mi*4+rr];
        float gj = acc[1][mi][rr] + (float)c1[mi*4+rr];
        float gf = acc[2][mi][rr] + (float)c2[mi*4+rr];
        float go = acc[3][mi][rr] + (float)c3[mi*4+rr];
        float hv = hst[mi][rr];
        if (s < Lr[mi][rr]) {
          float cn = sigf(gf + 1.0f)*cst[mi][rr] + sigf(gi)*tanh_f(gj);
          float hn = sigf(go)*tanh_f(cn);
          cst[mi][rr] = cn; hst[mi][rr] = hn; hv = hn;
        }
        hnv[mi][rr] = hv;
      }

    // pack h into tagged u64s (4 cols per u64, tag in LSB of first f16)
    u64* hw = hbuf + (size_t)(slot_w*2+dir)*NB*(NH/4);
#pragma unroll
    for (int mi=0;mi<2;++mi)
#pragma unroll
      for (int rr=0;rr<4;++rr) {
        f16 hf = (f16)hnv[mi][rr];
        u32 hb16 = (u32)__builtin_bit_cast(unsigned short, hf);
        if ((cc & 3) == 0) hb16 = (hb16 & 0xFFFEu) | tg_w;
        u32 nb = (u32)__shfl_down((int)hb16, 1);
        u32 pk = hb16 | (nb << 16);
        u32 pk2 = (u32)__shfl_down((int)pk, 2);
        if ((cc & 3) == 0) {
          u64 val = (u64)pk | ((u64)pk2 << 32);
          int b = mi*16 + q*4 + rr;
          __hip_atomic_store(hw + (size_t)b*(NH/4) + ((ncol0+cc)>>2), val,
                             __ATOMIC_RELAXED, __HIP_MEMORY_SCOPE_AGENT);
        }
      }

    // out stores — fire and forget (never drained inside the loop)
#pragma unroll
    for (int mi=0;mi<2;++mi)
#pragma unroll
      for (int rr=0;rr<4;++rr) {
        int L = Lr[mi][rr];
        if (s < L) {
          int b = mi*16 + q*4 + rr;
          int u = (dir==0) ? s : (L-1-s);
          outd[((size_t)b*NT + u)*(2*NH) + ncol0 + cc] = hnv[mi][rr];
        }
      }
  }
}

extern "C" void kernel_launch(void* const* d_in, const int* in_sizes, int n_in,
                              void* d_out, int out_size, void* d_ws, size_t ws_size,
                              hipStream_t stream) {
  (void)in_sizes; (void)n_in; (void)out_size; (void)ws_size;
  const float* x      = (const float*)d_in[0];
  const int*   seqlen = (const int*)  d_in[1];
  const float* Wfw    = (const float*)d_in[2];
  const float* bfw    = (const float*)d_in[3];
  const float* Wbw    = (const float*)d_in[4];
  const float* bbw    = (const float*)d_in[5];
  float* out = (float*)d_out;
  unsigned char* ws = (unsigned char*)d_ws;

  f16* xh   = (f16*)(ws + XH_OFF);
  f16* Wt   = (f16*)(ws + WT_OFF);
  f16* gxp  = (f16*)(ws + GX_OFF);
  u64* hbuf = (u64*)(ws + HB_OFF);

  size_t no = (size_t)NB*NT*2*NH/4;            // float4 count of d_out
  size_t nz = HB_BYTES/16;                     // uint4 count of hbuf
  k_zero<<<dim3(2048), dim3(256), 0, stream>>>((float4*)d_out, no,
                                               (uint4*)(ws + HB_OFF), nz);
  k_cvt<<<dim3((NB*NT*NF/4)/256), dim3(256), 0, stream>>>(x, xh);
  k_tw <<<dim3(4096), dim3(256), 0, stream>>>(Wfw, Wbw, Wt);
  k_gx <<<dim3(128, 16, 2), dim3(256), 0, stream>>>(xh, Wt, bfw, bbw, seqlen, gxp);
  k_rnn<<<dim3(16), dim3(256), 0, stream>>>(gxp, Wt, hbuf, seqlen, out);
}